// Round 17
// baseline (246.456 us; speedup 1.0000x reference)
//
#include <hip/hip_runtime.h>
#include <stdint.h>
#include <math.h>

#define NB 24
#define NC 128
#define NH 8
#define NDK 16
#define NL 512
#define NTOT (24*128*512)

typedef float f32x4 __attribute__((ext_vector_type(4)));
typedef short s16x4 __attribute__((ext_vector_type(4)));

__device__ inline f32x4 mfma_bf16_16x16x16(s16x4 a, s16x4 b, f32x4 c) {
#if defined(__HIP_DEVICE_COMPILE__)
#if __has_builtin(__builtin_amdgcn_mfma_f32_16x16x16bf16_1k)
  return __builtin_amdgcn_mfma_f32_16x16x16bf16_1k(a, b, c, 0, 0, 0);
#else
  return __builtin_amdgcn_mfma_f32_16x16x16_bf16(a, b, c, 0, 0, 0);
#endif
#else
  (void)a; (void)b;
  return c;  // host stub — never executed
#endif
}

__device__ inline unsigned short f2bf(float x) {   // RNE float->bf16
  uint32_t u = __float_as_uint(x);
  return (unsigned short)((u + 0x7FFFu + ((u >> 16) & 1u)) >> 16);
}
__device__ inline float bf2f(unsigned short s) {
  return __uint_as_float(((uint32_t)s) << 16);
}

// ---------------- threefry2x32 (JAX-compatible) ----------------
__host__ __device__ inline void tf2x32(uint32_t k0, uint32_t k1, uint32_t& x0, uint32_t& x1) {
  uint32_t ks2 = k0 ^ k1 ^ 0x1BD11BDAu;
  x0 += k0; x1 += k1;
#define TF_R(r) { x0 += x1; x1 = (x1 << r) | (x1 >> (32 - r)); x1 ^= x0; }
  TF_R(13) TF_R(15) TF_R(26) TF_R(6)
  x0 += k1;  x1 += ks2 + 1u;
  TF_R(17) TF_R(29) TF_R(16) TF_R(24)
  x0 += ks2; x1 += k0 + 2u;
  TF_R(13) TF_R(15) TF_R(26) TF_R(6)
  x0 += k0;  x1 += k1 + 3u;
  TF_R(17) TF_R(29) TF_R(16) TF_R(24)
  x0 += k1;  x1 += ks2 + 4u;
  TF_R(13) TF_R(15) TF_R(26) TF_R(6)
  x0 += ks2; x1 += k0 + 5u;
#undef TF_R
}

__device__ inline float drop_scale(uint32_t k0, uint32_t k1, uint32_t idx) {
  uint32_t x0 = 0u, x1 = idx;
  tf2x32(k0, k1, x0, x1);
  uint32_t bits = x0 ^ x1;
  float u = __uint_as_float((bits >> 9) | 0x3f800000u) - 1.0f;
  return (u < 0.9f) ? (1.0f / 0.9f) : 0.0f;
}

// ---------------- weight split arena ----------------
#define S0 (4*128*128)
#define SW (24*128*128)
#define SQ (8*24*16*128)
#define oPwH 0
#define oPwL (S0)
#define oWoH (2*S0)
#define oWoL (2*S0 + SW)
#define oWH  (2*S0 + 2*SW)
#define oWL  (2*S0 + 3*SW)
#define oQH  (2*S0 + 4*SW)
#define oQL  (2*S0 + 4*SW + SQ)
#define oKH  (2*S0 + 4*SW + 2*SQ)
#define oKL  (2*S0 + 4*SW + 3*SQ)
#define oVH  (2*S0 + 4*SW + 4*SQ)
#define oVL  (2*S0 + 4*SW + 5*SQ)
#define PREP_TOT (S0 + 2*SW + 3*SQ)   // 2031616 = 7936 * 256

__global__ __launch_bounds__(256) void prep_split_kernel(
    const float* __restrict__ pw_w, const float* __restrict__ Wo, const float* __restrict__ W,
    const float* __restrict__ Wq, const float* __restrict__ Wk, const float* __restrict__ Wv,
    unsigned short* __restrict__ ws) {
  int idx = blockIdx.x * 256 + threadIdx.x;
  const float* src; unsigned short *dh, *dl; int off;
  if (idx < S0)                { src = pw_w; dh = ws + oPwH; dl = ws + oPwL; off = idx; }
  else if (idx < S0 + SW)      { src = Wo;   dh = ws + oWoH; dl = ws + oWoL; off = idx - S0; }
  else if (idx < S0 + 2*SW)    { src = W;    dh = ws + oWH;  dl = ws + oWL;  off = idx - S0 - SW; }
  else if (idx < S0 + 2*SW + SQ)   { src = Wq; dh = ws + oQH; dl = ws + oQL; off = idx - S0 - 2*SW; }
  else if (idx < S0 + 2*SW + 2*SQ) { src = Wk; dh = ws + oKH; dl = ws + oKL; off = idx - S0 - 2*SW - SQ; }
  else                             { src = Wv; dh = ws + oVH; dl = ws + oVL; off = idx - S0 - 2*SW - 2*SQ; }
  float v = src[off];
  unsigned short hi = f2bf(v);
  dh[off] = hi;
  dl[off] = f2bf(v - bf2f(hi));
}

// ---------------- fused [pos-enc +] layernorm [+ depthwise conv] -> bf16 hi/lo ----------------
template<bool DO_CONV, bool ADD_PE>
__global__ __launch_bounds__(64) void norm_dw_kernel(const float* __restrict__ in,
                                                     float* __restrict__ cur_out,
                                                     unsigned short* __restrict__ oh,
                                                     unsigned short* __restrict__ ol,
                                                     const float* __restrict__ dww,
                                                     const float* __restrict__ dwb) {
  int row = blockIdx.x;           // b*NC + c
  int c = row & (NC - 1);
  int t = threadIdx.x;
  const float* rp = in + (size_t)row * NL;
  float4 v0 = ((const float4*)rp)[t * 2];
  float4 v1 = ((const float4*)rp)[t * 2 + 1];
  float xr[8] = {v0.x, v0.y, v0.z, v0.w, v1.x, v1.y, v1.z, v1.w};
  if (ADD_PE) {
    int ce = c & ~1;
    double base = exp(-(double)ce * 9.210340371976184 / 128.0); // ln(10000)
    float freq = (c & 1) ? -(float)base : (float)base;
    float phase = (c & 1) ? (float)(M_PI / 2.0) : 0.0f;
#pragma unroll
    for (int j = 0; j < 8; ++j)
      xr[j] += sinf(sinf((float)(t * 8 + j) * freq + phase));
    float4 o0 = make_float4(xr[0], xr[1], xr[2], xr[3]);
    float4 o1 = make_float4(xr[4], xr[5], xr[6], xr[7]);
    float4* cp = (float4*)(cur_out + (size_t)row * NL);
    cp[t * 2] = o0; cp[t * 2 + 1] = o1;
  }
  float s = 0.f;
#pragma unroll
  for (int j = 0; j < 8; ++j) s += xr[j];
#pragma unroll
  for (int off = 32; off >= 1; off >>= 1) s += __shfl_xor(s, off);
  float mean = s * (1.0f / 512.0f);
  float sq = 0.f;
#pragma unroll
  for (int j = 0; j < 8; ++j) { xr[j] -= mean; sq += xr[j] * xr[j]; }
#pragma unroll
  for (int off = 32; off >= 1; off >>= 1) sq += __shfl_xor(sq, off);
  float inv = 1.0f / (sqrtf(sq * (1.0f / 511.0f)) + 1e-6f);

  size_t obase = (size_t)row * NL + t * 8;
  if (!DO_CONV) {
#pragma unroll
    for (int j = 0; j < 8; ++j) {
      float o = xr[j] * inv;
      unsigned short hi = f2bf(o);
      oh[obase + j] = hi;
      ol[obase + j] = f2bf(o - bf2f(hi));
    }
  } else {
    __shared__ float rb[NL + 6];
    if (t < 3) { rb[t] = 0.f; rb[NL + 3 + t] = 0.f; }
#pragma unroll
    for (int j = 0; j < 8; ++j) rb[3 + t * 8 + j] = xr[j] * inv;
    __syncthreads();
    float w[7];
#pragma unroll
    for (int u = 0; u < 7; ++u) w[u] = dww[c * 7 + u];
    float bias = dwb[c];
#pragma unroll
    for (int j = 0; j < 8; ++j) {
      int l = t * 8 + j;
      float o = bias;
#pragma unroll
      for (int u = 0; u < 7; ++u) o += rb[l + u] * w[u];
      unsigned short hi = f2bf(o);
      oh[obase + j] = hi;
      ol[obase + j] = f2bf(o - bf2f(hi));
    }
  }
}

// ---------------- MFMA GEMM: X staged full-K once, loop 2 m-tiles ----------------
// EPI: 0 = bias+relu+resid+dropout, 1 = resid+dropout, 2 = relu+resid+dropout
template<int EPI, bool A_PER_B>
__global__ __launch_bounds__(256) void gemm_mfma_kernel(
    const unsigned short* __restrict__ AhB, const unsigned short* __restrict__ AlB,
    const unsigned short* __restrict__ XhB, const unsigned short* __restrict__ XlB,
    float* __restrict__ Y, const float* __restrict__ bias, const float* __restrict__ resid,
    uint32_t k0, uint32_t k1) {
  __shared__ unsigned short Xh[64][132], Xl[64][132];   // [n][k] full K (33.8 KB)
  __shared__ unsigned short Ah[64][68],  Al[64][68];    // [m][k] half K (17.4 KB)
  int b  = blockIdx.y;
  int l0 = blockIdx.x * 64;
  int t  = threadIdx.x;
  const int lane = t & 63, w = t >> 6;
  const int g = lane >> 4, j16 = lane & 15;
  const unsigned short* Abh = AhB + (A_PER_B ? (size_t)b * NC * NC : 0);
  const unsigned short* Abl = AlB + (A_PER_B ? (size_t)b * NC * NC : 0);
  const size_t xb = (size_t)b * NC * NL;

  { // stage X full-K: coalesced over n
    int n = t & 63, kq = (t >> 6) * 32;
    for (int kk = 0; kk < 32; ++kk) {
      int k = kq + kk;
      size_t src = xb + (size_t)k * NL + l0 + n;
      Xh[n][k] = XhB[src];
      Xl[n][k] = XlB[src];
    }
  }

  for (int mt = 0; mt < 2; ++mt) {
    int m0 = mt * 64;
    f32x4 acc[4] = {{0.f,0.f,0.f,0.f},{0.f,0.f,0.f,0.f},{0.f,0.f,0.f,0.f},{0.f,0.f,0.f,0.f}};
    for (int kc = 0; kc < 2; ++kc) {
      __syncthreads();   // guard prior A reads (and X staging on first pass)
#pragma unroll
      for (int i = 0; i < 4; ++i) {           // A chunk: ushort4 copies
        int id = t + i * 256;
        int r = id >> 4, u = (id & 15) << 2;
        *(s16x4*)&Ah[r][u] = *(const s16x4*)&Abh[(size_t)(m0 + r) * NC + kc * 64 + u];
        *(s16x4*)&Al[r][u] = *(const s16x4*)&Abl[(size_t)(m0 + r) * NC + kc * 64 + u];
      }
      __syncthreads();
#pragma unroll
      for (int ks = 0; ks < 4; ++ks) {
        int ka = ks * 16 + 4 * g;              // A local k
        int kx = kc * 64 + ka;                 // X global k
        s16x4 a_h = *(const s16x4*)&Ah[w * 16 + j16][ka];
        s16x4 a_l = *(const s16x4*)&Al[w * 16 + j16][ka];
#pragma unroll
        for (int nt = 0; nt < 4; ++nt) {
          s16x4 x_h = *(const s16x4*)&Xh[nt * 16 + j16][kx];
          s16x4 x_l = *(const s16x4*)&Xl[nt * 16 + j16][kx];
          acc[nt] = mfma_bf16_16x16x16(a_h, x_h, acc[nt]);
          acc[nt] = mfma_bf16_16x16x16(a_l, x_h, acc[nt]);
          acc[nt] = mfma_bf16_16x16x16(a_h, x_l, acc[nt]);
        }
      }
    }
    // epilogue for this m-tile (registers only)
#pragma unroll
    for (int nt = 0; nt < 4; ++nt) {
      int n = l0 + nt * 16 + j16;
#pragma unroll
      for (int r = 0; r < 4; ++r) {
        int m = m0 + w * 16 + 4 * g + r;
        float val = acc[nt][r] + ((EPI == 0) ? bias[m] : 0.0f);
        if (EPI == 0 || EPI == 2) val = fmaxf(val, 0.0f);
        size_t idx = ((size_t)b * NC + m) * NL + n;
        float v2 = resid[idx] + val;
        float ds = drop_scale(k0, k1, (uint32_t)idx);
        Y[idx] = (ds == 0.0f) ? 0.0f : (v2 / 0.9f);
      }
    }
  }
}

// ---------------- MFMA QKV projection: X staged once, loop 6 m-tiles ----------------
__global__ __launch_bounds__(256) void qkv_mfma_kernel(
    const unsigned short* __restrict__ wsp,
    const unsigned short* __restrict__ XhB, const unsigned short* __restrict__ XlB,
    unsigned short* __restrict__ qhw, unsigned short* __restrict__ qlw,
    unsigned short* __restrict__ khw, unsigned short* __restrict__ klw,
    unsigned short* __restrict__ vbw) {
  __shared__ unsigned short Xh[64][132], Xl[64][132];
  __shared__ unsigned short Ah[64][68],  Al[64][68];
  int b  = blockIdx.y;
  int l0 = blockIdx.x * 64;
  int t  = threadIdx.x;
  const int lane = t & 63, w = t >> 6;
  const int g = lane >> 4, j16 = lane & 15;
  const size_t xb = (size_t)b * NC * NL;

  { // stage X full-K once
    int n = t & 63, kq = (t >> 6) * 32;
    for (int kk = 0; kk < 32; ++kk) {
      int k = kq + kk;
      size_t src = xb + (size_t)k * NL + l0 + n;
      Xh[n][k] = XhB[src];
      Xl[n][k] = XlB[src];
    }
  }

  for (int mt = 0; mt < 6; ++mt) {
    int m0 = mt * 64;
    const int sel = m0 >> 7;
    const unsigned short* WpH = wsp + ((sel == 0) ? oQH : (sel == 1) ? oKH : oVH);
    const unsigned short* WpL = wsp + ((sel == 0) ? oQL : (sel == 1) ? oKL : oVL);
    f32x4 acc[4] = {{0.f,0.f,0.f,0.f},{0.f,0.f,0.f,0.f},{0.f,0.f,0.f,0.f},{0.f,0.f,0.f,0.f}};
    for (int kc = 0; kc < 2; ++kc) {
      __syncthreads();
#pragma unroll
      for (int i = 0; i < 4; ++i) {
        int id = t + i * 256;
        int r = id >> 4, u = (id & 15) << 2;
        int gr = m0 + r;
        int w_ = gr & 127, h = w_ >> 4, kk = w_ & 15;
        size_t rowoff = (((size_t)h * NB + b) * NDK + kk) * NC + kc * 64 + u;
        *(s16x4*)&Ah[r][u] = *(const s16x4*)&WpH[rowoff];
        *(s16x4*)&Al[r][u] = *(const s16x4*)&WpL[rowoff];
      }
      __syncthreads();
#pragma unroll
      for (int ks = 0; ks < 4; ++ks) {
        int ka = ks * 16 + 4 * g;
        int kx = kc * 64 + ka;
        s16x4 a_h = *(const s16x4*)&Ah[w * 16 + j16][ka];
        s16x4 a_l = *(const s16x4*)&Al[w * 16 + j16][ka];
#pragma unroll
        for (int nt = 0; nt < 4; ++nt) {
          s16x4 x_h = *(const s16x4*)&Xh[nt * 16 + j16][kx];
          s16x4 x_l = *(const s16x4*)&Xl[nt * 16 + j16][kx];
          acc[nt] = mfma_bf16_16x16x16(a_h, x_h, acc[nt]);
          acc[nt] = mfma_bf16_16x16x16(a_l, x_h, acc[nt]);
          acc[nt] = mfma_bf16_16x16x16(a_h, x_l, acc[nt]);
        }
      }
    }
#pragma unroll
    for (int nt = 0; nt < 4; ++nt) {
      int n = l0 + nt * 16 + j16;
#pragma unroll
      for (int r = 0; r < 4; ++r) {
        int grow = m0 + w * 16 + 4 * g + r;
        int w_ = grow & 127, h = w_ >> 4, kk = w_ & 15;
        size_t idx = (((size_t)h * NB + b) * NDK + kk) * NL + n;
        float v = acc[nt][r];
        if (sel == 0) {
          float sv = v * 0.25f;
          unsigned short hi = f2bf(sv);
          qhw[idx] = hi; qlw[idx] = f2bf(sv - bf2f(hi));
        } else if (sel == 1) {
          unsigned short hi = f2bf(v);
          khw[idx] = hi; klw[idx] = f2bf(v - bf2f(hi));
        } else {
          vbw[idx] = f2bf(v);
        }
      }
    }
  }
}

// ---------------- MFMA attention: Q/V staged once, loop 4 j-quarters ----------------
// grid: 192 blocks = hb; 256 thr = 4 waves; wave owns 2 j-tiles of 16 per quarter.
__global__ __launch_bounds__(256) void attn_kernel(const unsigned short* __restrict__ qh,
                                                   const unsigned short* __restrict__ ql,
                                                   const unsigned short* __restrict__ kh,
                                                   const unsigned short* __restrict__ kl,
                                                   const unsigned short* __restrict__ vb,
                                                   unsigned short* __restrict__ oh,
                                                   unsigned short* __restrict__ ol) {
  __shared__ unsigned short QtH[512][16], QtL[512][16];   // 32 KB, [i][k]
  __shared__ unsigned short KtH[128][16], KtL[128][16];   // 8 KB,  [j][k] (per quarter)
  __shared__ unsigned short Vt[16][520];                  // 16.25 KB, [v][i] (+pad)
  const int t = threadIdx.x;
  const int lane = t & 63, w = t >> 6;
  const int g = lane >> 4, j16 = lane & 15;
  const int hb = blockIdx.x;
  const int h = hb / NB, b = hb % NB;
  const size_t kb = (size_t)hb * NDK * NL;

  // stage Q hi/lo transposed [i][k] + V [v][i], once
  for (int n = 0; n < 32; ++n) {
    int e = n * 256 + t;
    int k = e >> 9, i = e & 511;
    QtH[i][k] = qh[kb + (size_t)k * NL + i];
    QtL[i][k] = ql[kb + (size_t)k * NL + i];
  }
  for (int n = 0; n < 16; ++n) {
    int e = n * 256 + t;
    int v = e >> 8, i2 = e & 255;
    *(uint32_t*)&Vt[v][i2 * 2] = *(const uint32_t*)&vb[kb + (size_t)v * NL + i2 * 2];
  }

  for (int jq = 0; jq < 4; ++jq) {
    const int j0 = jq * 128;
    __syncthreads();   // guard prior K fragment reads (and Q/V staging on first pass)
    for (int n = 0; n < 8; ++n) {
      int e = n * 256 + t;
      int k = e >> 7, j = e & 127;
      KtH[j][k] = kh[kb + (size_t)k * NL + j0 + j];
      KtL[j][k] = kl[kb + (size_t)k * NL + j0 + j];
    }
    __syncthreads();

    s16x4 KhiF[2], KloF[2];
#pragma unroll
    for (int q = 0; q < 2; ++q) {
      int jj = (w * 2 + q) * 16 + j16;
      KhiF[q] = *(const s16x4*)&KtH[jj][4 * g];
      KloF[q] = *(const s16x4*)&KtL[jj][4 * g];
    }

    float Mq[2] = {-INFINITY, -INFINITY};
    float lq[2] = {0.f, 0.f};
    f32x4 hC[2] = {{0.f, 0.f, 0.f, 0.f}, {0.f, 0.f, 0.f, 0.f}};

    for (int it = 0; it < 32; ++it) {
      s16x4 Qhi = *(const s16x4*)&QtH[it * 16 + j16][4 * g];
      s16x4 Qlo = *(const s16x4*)&QtL[it * 16 + j16][4 * g];
      s16x4 Vf  = *(const s16x4*)&Vt[j16][it * 16 + 4 * g];
#pragma unroll
      for (int q = 0; q < 2; ++q) {
        f32x4 S = {0.f, 0.f, 0.f, 0.f};
        S = mfma_bf16_16x16x16(Qhi, KhiF[q], S);
        S = mfma_bf16_16x16x16(Qlo, KhiF[q], S);
        S = mfma_bf16_16x16x16(Qhi, KloF[q], S);
        float tm = fmaxf(fmaxf(S[0], S[1]), fmaxf(S[2], S[3]));
        tm = fmaxf(tm, __shfl_xor(tm, 16));
        tm = fmaxf(tm, __shfl_xor(tm, 32));
        float Mn = fmaxf(Mq[q], tm);
        float corr = __expf(Mq[q] - Mn);
        Mq[q] = Mn;
        float p0 = __expf(S[0] - Mn), p1 = __expf(S[1] - Mn);
        float p2 = __expf(S[2] - Mn), p3 = __expf(S[3] - Mn);
        lq[q] = lq[q] * corr + ((p0 + p1) + (p2 + p3));
        hC[q] = hC[q] * corr;
        union { uint32_t u[2]; s16x4 s; } bp;
        bp.u[0] = (uint32_t)f2bf(p0) | ((uint32_t)f2bf(p1) << 16);
        bp.u[1] = (uint32_t)f2bf(p2) | ((uint32_t)f2bf(p3) << 16);
        hC[q] = mfma_bf16_16x16x16(Vf, bp.s, hC[q]);
      }
    }

#pragma unroll
    for (int q = 0; q < 2; ++q) {
      float l2 = lq[q] + __shfl_xor(lq[q], 16);
      float L  = l2 + __shfl_xor(l2, 32);
      float invL = 1.0f / L;
      int jglob = j0 + (w * 2 + q) * 16 + j16;
#pragma unroll
      for (int r = 0; r < 4; ++r) {
        float val = hC[q][r] * invL;
        size_t idx = ((size_t)b * NC + h * NDK + 4 * g + r) * NL + jglob;
        unsigned short hi = f2bf(val);
        oh[idx] = hi;
        ol[idx] = f2bf(val - bf2f(hi));
      }
    }
  }
}

// ---------------- launch ----------------
extern "C" void kernel_launch(void* const* d_in, const int* in_sizes, int n_in,
                              void* d_out, int out_size, void* d_ws, size_t ws_size,
                              hipStream_t stream) {
  (void)in_sizes; (void)n_in; (void)out_size; (void)ws_size;
  const float* x    = (const float*)d_in[0];
  const float* dw_w = (const float*)d_in[1];
  const float* dw_b = (const float*)d_in[2];
  const float* pw_w = (const float*)d_in[3];
  const float* pw_b = (const float*)d_in[4];
  const float* Wq   = (const float*)d_in[5];
  const float* Wk   = (const float*)d_in[6];
  const float* Wv   = (const float*)d_in[7];
  const float* Wo   = (const float*)d_in[8];
  const float* W    = (const float*)d_in[9];
  float* out = (float*)d_out;

  const size_t N = NTOT;
  float* cur = (float*)d_ws;                      // N floats
  unsigned short* XhB = (unsigned short*)(cur + N);
  unsigned short* XlB = XhB + N;
  unsigned short* qh  = XlB + N;
  unsigned short* ql  = qh + N;
  unsigned short* kh  = ql + N;
  unsigned short* kl  = kh + N;
  unsigned short* vb  = kl + N;
  unsigned short* wsp = vb + N;                   // weight-split arena (PREP ushorts)

  uint32_t fk0[6], fk1[6];
  for (int i = 0; i < 6; ++i) {
    uint32_t a = 0u, bb = (uint32_t)i;
    tf2x32(0u, 7u, a, bb);
    fk0[i] = a; fk1[i] = bb;
  }

  prep_split_kernel<<<PREP_TOT / 256, 256, 0, stream>>>(pw_w, Wo, W, Wq, Wk, Wv, wsp);

  // conv block 0: pos-enc fused
  norm_dw_kernel<true, true><<<NB * NC, 64, 0, stream>>>(x, cur, XhB, XlB, dw_w, dw_b);
  gemm_mfma_kernel<0, false><<<dim3(8, NB), 256, 0, stream>>>(
      wsp + oPwH, wsp + oPwL, XhB, XlB, cur, pw_b, cur, fk0[0], fk1[0]);
  for (int ci = 1; ci < 4; ++ci) {
    norm_dw_kernel<true, false><<<NB * NC, 64, 0, stream>>>(cur, nullptr, XhB, XlB,
                                                            dw_w + ci * NC * 7, dw_b + ci * NC);
    gemm_mfma_kernel<0, false><<<dim3(8, NB), 256, 0, stream>>>(
        wsp + oPwH + (size_t)ci * NC * NC, wsp + oPwL + (size_t)ci * NC * NC,
        XhB, XlB, cur, pw_b + ci * NC, cur, fk0[ci], fk1[ci]);
  }

  norm_dw_kernel<false, false><<<NB * NC, 64, 0, stream>>>(cur, nullptr, XhB, XlB, nullptr, nullptr);
  qkv_mfma_kernel<<<dim3(8, NB), 256, 0, stream>>>(wsp, XhB, XlB, qh, ql, kh, kl, vb);
  attn_kernel<<<NH * NB, 256, 0, stream>>>(qh, ql, kh, kl, vb, XhB, XlB);
  gemm_mfma_kernel<1, true><<<dim3(8, NB), 256, 0, stream>>>(
      wsp + oWoH, wsp + oWoL, XhB, XlB, cur, nullptr, cur, fk0[4], fk1[4]);

  norm_dw_kernel<false, false><<<NB * NC, 64, 0, stream>>>(cur, nullptr, XhB, XlB, nullptr, nullptr);
  gemm_mfma_kernel<2, true><<<dim3(8, NB), 256, 0, stream>>>(
      wsp + oWH, wsp + oWL, XhB, XlB, out, nullptr, cur, fk0[5], fk1[5]);
}

// Round 19
// 191.008 us; speedup vs baseline: 1.2903x; 1.2903x over previous
//
#include <hip/hip_runtime.h>
#include <stdint.h>
#include <math.h>

#define NB 24
#define NC 128
#define NH 8
#define NDK 16
#define NL 512
#define NTOT (24*128*512)

typedef float f32x4 __attribute__((ext_vector_type(4)));
typedef short s16x4 __attribute__((ext_vector_type(4)));

__device__ inline f32x4 mfma_bf16_16x16x16(s16x4 a, s16x4 b, f32x4 c) {
#if defined(__HIP_DEVICE_COMPILE__)
#if __has_builtin(__builtin_amdgcn_mfma_f32_16x16x16bf16_1k)
  return __builtin_amdgcn_mfma_f32_16x16x16bf16_1k(a, b, c, 0, 0, 0);
#else
  return __builtin_amdgcn_mfma_f32_16x16x16_bf16(a, b, c, 0, 0, 0);
#endif
#else
  (void)a; (void)b;
  return c;  // host stub — never executed
#endif
}

__device__ inline unsigned short f2bf(float x) {   // RNE float->bf16
  uint32_t u = __float_as_uint(x);
  return (unsigned short)((u + 0x7FFFu + ((u >> 16) & 1u)) >> 16);
}
__device__ inline float bf2f(unsigned short s) {
  return __uint_as_float(((uint32_t)s) << 16);
}

// ---------------- threefry2x32 (JAX-compatible) ----------------
__host__ __device__ inline void tf2x32(uint32_t k0, uint32_t k1, uint32_t& x0, uint32_t& x1) {
  uint32_t ks2 = k0 ^ k1 ^ 0x1BD11BDAu;
  x0 += k0; x1 += k1;
#define TF_R(r) { x0 += x1; x1 = (x1 << r) | (x1 >> (32 - r)); x1 ^= x0; }
  TF_R(13) TF_R(15) TF_R(26) TF_R(6)
  x0 += k1;  x1 += ks2 + 1u;
  TF_R(17) TF_R(29) TF_R(16) TF_R(24)
  x0 += ks2; x1 += k0 + 2u;
  TF_R(13) TF_R(15) TF_R(26) TF_R(6)
  x0 += k0;  x1 += k1 + 3u;
  TF_R(17) TF_R(29) TF_R(16) TF_R(24)
  x0 += k1;  x1 += ks2 + 4u;
  TF_R(13) TF_R(15) TF_R(26) TF_R(6)
  x0 += ks2; x1 += k0 + 5u;
#undef TF_R
}

__device__ inline float drop_scale(uint32_t k0, uint32_t k1, uint32_t idx) {
  uint32_t x0 = 0u, x1 = idx;
  tf2x32(k0, k1, x0, x1);
  uint32_t bits = x0 ^ x1;
  float u = __uint_as_float((bits >> 9) | 0x3f800000u) - 1.0f;
  return (u < 0.9f) ? (1.0f / 0.9f) : 0.0f;
}

// ---------------- weight split arena ----------------
#define S0 (4*128*128)
#define SW (24*128*128)
#define SQ (8*24*16*128)
#define oPwH 0
#define oPwL (S0)
#define oWoH (2*S0)
#define oWoL (2*S0 + SW)
#define oWH  (2*S0 + 2*SW)
#define oWL  (2*S0 + 3*SW)
#define oQH  (2*S0 + 4*SW)
#define oQL  (2*S0 + 4*SW + SQ)
#define oKH  (2*S0 + 4*SW + 2*SQ)
#define oKL  (2*S0 + 4*SW + 3*SQ)
#define oVH  (2*S0 + 4*SW + 4*SQ)
#define oVL  (2*S0 + 4*SW + 5*SQ)
#define PREP_TOT (S0 + 2*SW + 3*SQ)   // 2031616 = 7936 * 256

__global__ __launch_bounds__(256) void prep_split_kernel(
    const float* __restrict__ pw_w, const float* __restrict__ Wo, const float* __restrict__ W,
    const float* __restrict__ Wq, const float* __restrict__ Wk, const float* __restrict__ Wv,
    unsigned short* __restrict__ ws) {
  int idx = blockIdx.x * 256 + threadIdx.x;
  const float* src; unsigned short *dh, *dl; int off;
  if (idx < S0)                { src = pw_w; dh = ws + oPwH; dl = ws + oPwL; off = idx; }
  else if (idx < S0 + SW)      { src = Wo;   dh = ws + oWoH; dl = ws + oWoL; off = idx - S0; }
  else if (idx < S0 + 2*SW)    { src = W;    dh = ws + oWH;  dl = ws + oWL;  off = idx - S0 - SW; }
  else if (idx < S0 + 2*SW + SQ)   { src = Wq; dh = ws + oQH; dl = ws + oQL; off = idx - S0 - 2*SW; }
  else if (idx < S0 + 2*SW + 2*SQ) { src = Wk; dh = ws + oKH; dl = ws + oKL; off = idx - S0 - 2*SW - SQ; }
  else                             { src = Wv; dh = ws + oVH; dl = ws + oVL; off = idx - S0 - 2*SW - 2*SQ; }
  float v = src[off];
  unsigned short hi = f2bf(v);
  dh[off] = hi;
  dl[off] = f2bf(v - bf2f(hi));
}

// ---------------- fused [pos-enc +] layernorm [+ depthwise conv] -> bf16 hi/lo ----------------
template<bool DO_CONV, bool ADD_PE>
__global__ __launch_bounds__(64) void norm_dw_kernel(const float* __restrict__ in,
                                                     float* __restrict__ cur_out,
                                                     unsigned short* __restrict__ oh,
                                                     unsigned short* __restrict__ ol,
                                                     const float* __restrict__ dww,
                                                     const float* __restrict__ dwb) {
  int row = blockIdx.x;           // b*NC + c
  int c = row & (NC - 1);
  int t = threadIdx.x;
  const float* rp = in + (size_t)row * NL;
  float4 v0 = ((const float4*)rp)[t * 2];
  float4 v1 = ((const float4*)rp)[t * 2 + 1];
  float xr[8] = {v0.x, v0.y, v0.z, v0.w, v1.x, v1.y, v1.z, v1.w};
  if (ADD_PE) {
    int ce = c & ~1;
    double base = exp(-(double)ce * 9.210340371976184 / 128.0); // ln(10000)
    float freq = (c & 1) ? -(float)base : (float)base;
    float phase = (c & 1) ? (float)(M_PI / 2.0) : 0.0f;
#pragma unroll
    for (int j = 0; j < 8; ++j)
      xr[j] += sinf(sinf((float)(t * 8 + j) * freq + phase));
    float4 o0 = make_float4(xr[0], xr[1], xr[2], xr[3]);
    float4 o1 = make_float4(xr[4], xr[5], xr[6], xr[7]);
    float4* cp = (float4*)(cur_out + (size_t)row * NL);
    cp[t * 2] = o0; cp[t * 2 + 1] = o1;
  }
  float s = 0.f;
#pragma unroll
  for (int j = 0; j < 8; ++j) s += xr[j];
#pragma unroll
  for (int off = 32; off >= 1; off >>= 1) s += __shfl_xor(s, off);
  float mean = s * (1.0f / 512.0f);
  float sq = 0.f;
#pragma unroll
  for (int j = 0; j < 8; ++j) { xr[j] -= mean; sq += xr[j] * xr[j]; }
#pragma unroll
  for (int off = 32; off >= 1; off >>= 1) sq += __shfl_xor(sq, off);
  float inv = 1.0f / (sqrtf(sq * (1.0f / 511.0f)) + 1e-6f);

  size_t obase = (size_t)row * NL + t * 8;
  if (!DO_CONV) {
#pragma unroll
    for (int j = 0; j < 8; ++j) {
      float o = xr[j] * inv;
      unsigned short hi = f2bf(o);
      oh[obase + j] = hi;
      ol[obase + j] = f2bf(o - bf2f(hi));
    }
  } else {
    __shared__ float rb[NL + 6];
    if (t < 3) { rb[t] = 0.f; rb[NL + 3 + t] = 0.f; }
#pragma unroll
    for (int j = 0; j < 8; ++j) rb[3 + t * 8 + j] = xr[j] * inv;
    __syncthreads();
    float w[7];
#pragma unroll
    for (int u = 0; u < 7; ++u) w[u] = dww[c * 7 + u];
    float bias = dwb[c];
#pragma unroll
    for (int j = 0; j < 8; ++j) {
      int l = t * 8 + j;
      float o = bias;
#pragma unroll
      for (int u = 0; u < 7; ++u) o += rb[l + u] * w[u];
      unsigned short hi = f2bf(o);
      oh[obase + j] = hi;
      ol[obase + j] = f2bf(o - bf2f(hi));
    }
  }
}

// ---------------- MFMA GEMM with pre-split operands ----------------
// A (hi/lo ushort) [M][K]; X (hi/lo ushort) [b][K][L]. 64x64 out per block, 4 waves.
// EPI: 0 = bias+relu+resid+dropout, 1 = resid+dropout, 2 = relu+resid+dropout
template<int EPI, bool A_PER_B>
__global__ __launch_bounds__(256) void gemm_mfma_kernel(
    const unsigned short* __restrict__ AhB, const unsigned short* __restrict__ AlB,
    const unsigned short* __restrict__ XhB, const unsigned short* __restrict__ XlB,
    float* __restrict__ Y, const float* __restrict__ bias, const float* __restrict__ resid,
    uint32_t k0, uint32_t k1) {
  __shared__ unsigned short Ah[64][68], Al[64][68];   // [m][k]
  __shared__ unsigned short Xh[64][68], Xl[64][68];   // [n][k]
  int b  = blockIdx.z;
  int m0 = blockIdx.y * 64;
  int l0 = blockIdx.x * 64;
  int t  = threadIdx.x;
  const int lane = t & 63, w = t >> 6;
  const int g = lane >> 4, j16 = lane & 15;
  const unsigned short* Abh = AhB + (A_PER_B ? (size_t)b * NC * NC : 0);
  const unsigned short* Abl = AlB + (A_PER_B ? (size_t)b * NC * NC : 0);
  const size_t xb = (size_t)b * NC * NL;

  f32x4 acc[4] = {{0.f,0.f,0.f,0.f},{0.f,0.f,0.f,0.f},{0.f,0.f,0.f,0.f},{0.f,0.f,0.f,0.f}};

  for (int kc = 0; kc < 2; ++kc) {
#pragma unroll
    for (int i = 0; i < 4; ++i) {           // A tile: ushort4 copies
      int id = t + i * 256;
      int r = id >> 4, u = (id & 15) << 2;
      *(s16x4*)&Ah[r][u] = *(const s16x4*)&Abh[(size_t)(m0 + r) * NC + kc * 64 + u];
      *(s16x4*)&Al[r][u] = *(const s16x4*)&Abl[(size_t)(m0 + r) * NC + kc * 64 + u];
    }
    {
      int n = t & 63, kq = (t >> 6) * 16;
#pragma unroll
      for (int kk = 0; kk < 16; ++kk) {
        int k = kq + kk;
        size_t src = xb + (size_t)(kc * 64 + k) * NL + l0 + n;
        Xh[n][k] = XhB[src];
        Xl[n][k] = XlB[src];
      }
    }
    __syncthreads();
#pragma unroll
    for (int ks = 0; ks < 4; ++ks) {
      int ko = ks * 16 + 4 * g;
      s16x4 a_h = *(const s16x4*)&Ah[w * 16 + j16][ko];
      s16x4 a_l = *(const s16x4*)&Al[w * 16 + j16][ko];
#pragma unroll
      for (int nt = 0; nt < 4; ++nt) {
        s16x4 x_h = *(const s16x4*)&Xh[nt * 16 + j16][ko];
        s16x4 x_l = *(const s16x4*)&Xl[nt * 16 + j16][ko];
        acc[nt] = mfma_bf16_16x16x16(a_h, x_h, acc[nt]);
        acc[nt] = mfma_bf16_16x16x16(a_l, x_h, acc[nt]);
        acc[nt] = mfma_bf16_16x16x16(a_h, x_l, acc[nt]);
      }
    }
    __syncthreads();
  }

#pragma unroll
  for (int nt = 0; nt < 4; ++nt) {
    int n = l0 + nt * 16 + j16;
#pragma unroll
    for (int r = 0; r < 4; ++r) {
      int m = m0 + w * 16 + 4 * g + r;
      float val = acc[nt][r] + ((EPI == 0) ? bias[m] : 0.0f);
      if (EPI == 0 || EPI == 2) val = fmaxf(val, 0.0f);
      size_t idx = ((size_t)b * NC + m) * NL + n;
      float v2 = resid[idx] + val;
      float ds = drop_scale(k0, k1, (uint32_t)idx);
      Y[idx] = (ds == 0.0f) ? 0.0f : (v2 / 0.9f);
    }
  }
}

// ---------------- MFMA QKV projection with pre-split operands ----------------
__global__ __launch_bounds__(256) void qkv_mfma_kernel(
    const unsigned short* __restrict__ wsp,
    const unsigned short* __restrict__ XhB, const unsigned short* __restrict__ XlB,
    unsigned short* __restrict__ qhw, unsigned short* __restrict__ qlw,
    unsigned short* __restrict__ khw, unsigned short* __restrict__ klw,
    unsigned short* __restrict__ vbw) {
  __shared__ unsigned short Ah[64][68], Al[64][68];
  __shared__ unsigned short Xh[64][68], Xl[64][68];
  int b  = blockIdx.z;
  int m0 = blockIdx.y * 64;          // sel = m0>>7 uniform per block
  int l0 = blockIdx.x * 64;
  int t  = threadIdx.x;
  const int lane = t & 63, w = t >> 6;
  const int g = lane >> 4, j16 = lane & 15;
  const int sel = m0 >> 7;
  const unsigned short* WpH = wsp + ((sel == 0) ? oQH : (sel == 1) ? oKH : oVH);
  const unsigned short* WpL = wsp + ((sel == 0) ? oQL : (sel == 1) ? oKL : oVL);
  const size_t xb = (size_t)b * NC * NL;

  f32x4 acc[4] = {{0.f,0.f,0.f,0.f},{0.f,0.f,0.f,0.f},{0.f,0.f,0.f,0.f},{0.f,0.f,0.f,0.f}};

  for (int kc = 0; kc < 2; ++kc) {
#pragma unroll
    for (int i = 0; i < 4; ++i) {
      int id = t + i * 256;
      int r = id >> 4, u = (id & 15) << 2;
      int gr = m0 + r;
      int w_ = gr & 127, h = w_ >> 4, kk = w_ & 15;
      size_t rowoff = (((size_t)h * NB + b) * NDK + kk) * NC + kc * 64 + u;
      *(s16x4*)&Ah[r][u] = *(const s16x4*)&WpH[rowoff];
      *(s16x4*)&Al[r][u] = *(const s16x4*)&WpL[rowoff];
    }
    {
      int n = t & 63, kq = (t >> 6) * 16;
#pragma unroll
      for (int kk = 0; kk < 16; ++kk) {
        int k = kq + kk;
        size_t src = xb + (size_t)(kc * 64 + k) * NL + l0 + n;
        Xh[n][k] = XhB[src];
        Xl[n][k] = XlB[src];
      }
    }
    __syncthreads();
#pragma unroll
    for (int ks = 0; ks < 4; ++ks) {
      int ko = ks * 16 + 4 * g;
      s16x4 a_h = *(const s16x4*)&Ah[w * 16 + j16][ko];
      s16x4 a_l = *(const s16x4*)&Al[w * 16 + j16][ko];
#pragma unroll
      for (int nt = 0; nt < 4; ++nt) {
        s16x4 x_h = *(const s16x4*)&Xh[nt * 16 + j16][ko];
        s16x4 x_l = *(const s16x4*)&Xl[nt * 16 + j16][ko];
        acc[nt] = mfma_bf16_16x16x16(a_h, x_h, acc[nt]);
        acc[nt] = mfma_bf16_16x16x16(a_l, x_h, acc[nt]);
        acc[nt] = mfma_bf16_16x16x16(a_h, x_l, acc[nt]);
      }
    }
    __syncthreads();
  }

#pragma unroll
  for (int nt = 0; nt < 4; ++nt) {
    int n = l0 + nt * 16 + j16;
#pragma unroll
    for (int r = 0; r < 4; ++r) {
      int grow = m0 + w * 16 + 4 * g + r;
      int w_ = grow & 127, h = w_ >> 4, kk = w_ & 15;
      size_t idx = (((size_t)h * NB + b) * NDK + kk) * NL + n;
      float v = acc[nt][r];
      if (sel == 0) {
        float sv = v * 0.25f;
        unsigned short hi = f2bf(sv);
        qhw[idx] = hi; qlw[idx] = f2bf(sv - bf2f(hi));
      } else if (sel == 1) {
        unsigned short hi = f2bf(v);
        khw[idx] = hi; klw[idx] = f2bf(v - bf2f(hi));
      } else {
        vbw[idx] = f2bf(v);
      }
    }
  }
}

// ---------------- MFMA attention, fully LDS-resident (softmax over query axis i) ----------------
// grid: dim3(4, H*B); 256 thr = 4 waves; wave owns 2 j-tiles of 16. Zero barriers in loop.
// LDS rows padded to 18 ushorts (stride 36 B, bank stride 9 coprime 32) -> conflict-free Qt reads.
__global__ __launch_bounds__(256) void attn_kernel(const unsigned short* __restrict__ qh,
                                                   const unsigned short* __restrict__ ql,
                                                   const unsigned short* __restrict__ kh,
                                                   const unsigned short* __restrict__ kl,
                                                   const unsigned short* __restrict__ vb,
                                                   unsigned short* __restrict__ oh,
                                                   unsigned short* __restrict__ ol) {
  __shared__ unsigned short QtH[512][18], QtL[512][18];   // 18 KB each, [i][k] (+2 pad)
  __shared__ unsigned short KtH[128][18], KtL[128][18];   // 4.5 KB each, [j][k] (+2 pad)
  __shared__ unsigned short Vt[16][520];                  // 16.25 KB,   [v][i] (+pad)
  const int t = threadIdx.x;
  const int lane = t & 63, w = t >> 6;
  const int g = lane >> 4, j16 = lane & 15;
  const int hb = blockIdx.y, jq = blockIdx.x;
  const int j0 = jq * 128;
  const int h = hb / NB, b = hb % NB;
  const size_t kb = (size_t)hb * NDK * NL;

  // stage Q hi/lo transposed [i][k] (coalesced over i)
  for (int n = 0; n < 32; ++n) {
    int e = n * 256 + t;
    int k = e >> 9, i = e & 511;
    QtH[i][k] = qh[kb + (size_t)k * NL + i];
    QtL[i][k] = ql[kb + (size_t)k * NL + i];
  }
  // stage V [v][i] (uint32 = 2 ushorts)
  for (int n = 0; n < 16; ++n) {
    int e = n * 256 + t;            // 4096 u32 units
    int v = e >> 8, i2 = e & 255;
    *(uint32_t*)&Vt[v][i2 * 2] = *(const uint32_t*)&vb[kb + (size_t)v * NL + i2 * 2];
  }
  // stage K quarter [j][k]
  for (int n = 0; n < 8; ++n) {
    int e = n * 256 + t;
    int k = e >> 7, j = e & 127;
    KtH[j][k] = kh[kb + (size_t)k * NL + j0 + j];
    KtL[j][k] = kl[kb + (size_t)k * NL + j0 + j];
  }
  __syncthreads();

  s16x4 KhiF[2], KloF[2];
#pragma unroll
  for (int q = 0; q < 2; ++q) {
    int jj = (w * 2 + q) * 16 + j16;
    KhiF[q] = *(const s16x4*)&KtH[jj][4 * g];
    KloF[q] = *(const s16x4*)&KtL[jj][4 * g];
  }

  float Mq[2] = {-INFINITY, -INFINITY};
  float lq[2] = {0.f, 0.f};
  f32x4 hC[2] = {{0.f, 0.f, 0.f, 0.f}, {0.f, 0.f, 0.f, 0.f}};

  for (int it = 0; it < 32; ++it) {
    s16x4 Qhi = *(const s16x4*)&QtH[it * 16 + j16][4 * g];
    s16x4 Qlo = *(const s16x4*)&QtL[it * 16 + j16][4 * g];
    s16x4 Vf  = *(const s16x4*)&Vt[j16][it * 16 + 4 * g];
#pragma unroll
    for (int q = 0; q < 2; ++q) {
      f32x4 S = {0.f, 0.f, 0.f, 0.f};
      S = mfma_bf16_16x16x16(Qhi, KhiF[q], S);
      S = mfma_bf16_16x16x16(Qlo, KhiF[q], S);
      S = mfma_bf16_16x16x16(Qhi, KloF[q], S);
      float tm = fmaxf(fmaxf(S[0], S[1]), fmaxf(S[2], S[3]));
      tm = fmaxf(tm, __shfl_xor(tm, 16));
      tm = fmaxf(tm, __shfl_xor(tm, 32));
      float Mn = fmaxf(Mq[q], tm);
      float corr = __expf(Mq[q] - Mn);
      Mq[q] = Mn;
      float p0 = __expf(S[0] - Mn), p1 = __expf(S[1] - Mn);
      float p2 = __expf(S[2] - Mn), p3 = __expf(S[3] - Mn);
      lq[q] = lq[q] * corr + ((p0 + p1) + (p2 + p3));
      hC[q] = hC[q] * corr;
      union { uint32_t u[2]; s16x4 s; } bp;
      bp.u[0] = (uint32_t)f2bf(p0) | ((uint32_t)f2bf(p1) << 16);
      bp.u[1] = (uint32_t)f2bf(p2) | ((uint32_t)f2bf(p3) << 16);
      hC[q] = mfma_bf16_16x16x16(Vf, bp.s, hC[q]);
    }
  }

#pragma unroll
  for (int q = 0; q < 2; ++q) {
    float l2 = lq[q] + __shfl_xor(lq[q], 16);
    float L  = l2 + __shfl_xor(l2, 32);
    float invL = 1.0f / L;
    int jglob = j0 + (w * 2 + q) * 16 + j16;
#pragma unroll
    for (int r = 0; r < 4; ++r) {
      float val = hC[q][r] * invL;
      size_t idx = ((size_t)b * NC + h * NDK + 4 * g + r) * NL + jglob;
      unsigned short hi = f2bf(val);
      oh[idx] = hi;
      ol[idx] = f2bf(val - bf2f(hi));
    }
  }
}

// ---------------- launch ----------------
extern "C" void kernel_launch(void* const* d_in, const int* in_sizes, int n_in,
                              void* d_out, int out_size, void* d_ws, size_t ws_size,
                              hipStream_t stream) {
  (void)in_sizes; (void)n_in; (void)out_size; (void)ws_size;
  const float* x    = (const float*)d_in[0];
  const float* dw_w = (const float*)d_in[1];
  const float* dw_b = (const float*)d_in[2];
  const float* pw_w = (const float*)d_in[3];
  const float* pw_b = (const float*)d_in[4];
  const float* Wq   = (const float*)d_in[5];
  const float* Wk   = (const float*)d_in[6];
  const float* Wv   = (const float*)d_in[7];
  const float* Wo   = (const float*)d_in[8];
  const float* W    = (const float*)d_in[9];
  float* out = (float*)d_out;

  const size_t N = NTOT;
  float* cur = (float*)d_ws;                      // N floats
  unsigned short* XhB = (unsigned short*)(cur + N);
  unsigned short* XlB = XhB + N;
  unsigned short* qh  = XlB + N;
  unsigned short* ql  = qh + N;
  unsigned short* kh  = ql + N;
  unsigned short* kl  = kh + N;
  unsigned short* vb  = kl + N;
  unsigned short* wsp = vb + N;                   // weight-split arena (PREP ushorts)

  uint32_t fk0[6], fk1[6];
  for (int i = 0; i < 6; ++i) {
    uint32_t a = 0u, bb = (uint32_t)i;
    tf2x32(0u, 7u, a, bb);
    fk0[i] = a; fk1[i] = bb;
  }

  prep_split_kernel<<<PREP_TOT / 256, 256, 0, stream>>>(pw_w, Wo, W, Wq, Wk, Wv, wsp);

  // conv block 0: pos-enc fused
  norm_dw_kernel<true, true><<<NB * NC, 64, 0, stream>>>(x, cur, XhB, XlB, dw_w, dw_b);
  gemm_mfma_kernel<0, false><<<dim3(8, 2, NB), 256, 0, stream>>>(
      wsp + oPwH, wsp + oPwL, XhB, XlB, cur, pw_b, cur, fk0[0], fk1[0]);
  for (int ci = 1; ci < 4; ++ci) {
    norm_dw_kernel<true, false><<<NB * NC, 64, 0, stream>>>(cur, nullptr, XhB, XlB,
                                                            dw_w + ci * NC * 7, dw_b + ci * NC);
    gemm_mfma_kernel<0, false><<<dim3(8, 2, NB), 256, 0, stream>>>(
        wsp + oPwH + (size_t)ci * NC * NC, wsp + oPwL + (size_t)ci * NC * NC,
        XhB, XlB, cur, pw_b + ci * NC, cur, fk0[ci], fk1[ci]);
  }

  norm_dw_kernel<false, false><<<NB * NC, 64, 0, stream>>>(cur, nullptr, XhB, XlB, nullptr, nullptr);
  qkv_mfma_kernel<<<dim3(8, 6, NB), 256, 0, stream>>>(wsp, XhB, XlB, qh, ql, kh, kl, vb);
  attn_kernel<<<dim3(4, NH * NB), 256, 0, stream>>>(qh, ql, kh, kl, vb, XhB, XlB);
  gemm_mfma_kernel<1, true><<<dim3(8, 2, NB), 256, 0, stream>>>(
      wsp + oWoH, wsp + oWoL, XhB, XlB, cur, nullptr, cur, fk0[4], fk1[4]);

  norm_dw_kernel<false, false><<<NB * NC, 64, 0, stream>>>(cur, nullptr, XhB, XlB, nullptr, nullptr);
  gemm_mfma_kernel<2, true><<<dim3(8, 2, NB), 256, 0, stream>>>(
      wsp + oWH, wsp + oWL, XhB, XlB, out, nullptr, cur, fk0[5], fk1[5]);
}

// Round 20
// 190.680 us; speedup vs baseline: 1.2925x; 1.0017x over previous
//
#include <hip/hip_runtime.h>
#include <stdint.h>
#include <math.h>

#define NB 24
#define NC 128
#define NH 8
#define NDK 16
#define NL 512
#define NTOT (24*128*512)

typedef float f32x4 __attribute__((ext_vector_type(4)));
typedef short s16x4 __attribute__((ext_vector_type(4)));

__device__ inline f32x4 mfma_bf16_16x16x16(s16x4 a, s16x4 b, f32x4 c) {
#if defined(__HIP_DEVICE_COMPILE__)
#if __has_builtin(__builtin_amdgcn_mfma_f32_16x16x16bf16_1k)
  return __builtin_amdgcn_mfma_f32_16x16x16bf16_1k(a, b, c, 0, 0, 0);
#else
  return __builtin_amdgcn_mfma_f32_16x16x16_bf16(a, b, c, 0, 0, 0);
#endif
#else
  (void)a; (void)b;
  return c;  // host stub — never executed
#endif
}

__device__ inline unsigned short f2bf(float x) {   // RNE float->bf16
  uint32_t u = __float_as_uint(x);
  return (unsigned short)((u + 0x7FFFu + ((u >> 16) & 1u)) >> 16);
}
__device__ inline float bf2f(unsigned short s) {
  return __uint_as_float(((uint32_t)s) << 16);
}

// ---------------- threefry2x32 (JAX-compatible) ----------------
__host__ __device__ inline void tf2x32(uint32_t k0, uint32_t k1, uint32_t& x0, uint32_t& x1) {
  uint32_t ks2 = k0 ^ k1 ^ 0x1BD11BDAu;
  x0 += k0; x1 += k1;
#define TF_R(r) { x0 += x1; x1 = (x1 << r) | (x1 >> (32 - r)); x1 ^= x0; }
  TF_R(13) TF_R(15) TF_R(26) TF_R(6)
  x0 += k1;  x1 += ks2 + 1u;
  TF_R(17) TF_R(29) TF_R(16) TF_R(24)
  x0 += ks2; x1 += k0 + 2u;
  TF_R(13) TF_R(15) TF_R(26) TF_R(6)
  x0 += k0;  x1 += k1 + 3u;
  TF_R(17) TF_R(29) TF_R(16) TF_R(24)
  x0 += k1;  x1 += ks2 + 4u;
  TF_R(13) TF_R(15) TF_R(26) TF_R(6)
  x0 += ks2; x1 += k0 + 5u;
#undef TF_R
}

__device__ inline float drop_scale(uint32_t k0, uint32_t k1, uint32_t idx) {
  uint32_t x0 = 0u, x1 = idx;
  tf2x32(k0, k1, x0, x1);
  uint32_t bits = x0 ^ x1;
  float u = __uint_as_float((bits >> 9) | 0x3f800000u) - 1.0f;
  return (u < 0.9f) ? (1.0f / 0.9f) : 0.0f;
}

// ---------------- weight split arena ----------------
#define S0 (4*128*128)
#define SW (24*128*128)
#define SQ (8*24*16*128)
#define oPwH 0
#define oPwL (S0)
#define oWoH (2*S0)
#define oWoL (2*S0 + SW)
#define oWH  (2*S0 + 2*SW)
#define oWL  (2*S0 + 3*SW)
#define oQH  (2*S0 + 4*SW)
#define oQL  (2*S0 + 4*SW + SQ)
#define oKH  (2*S0 + 4*SW + 2*SQ)
#define oKL  (2*S0 + 4*SW + 3*SQ)
#define oVH  (2*S0 + 4*SW + 4*SQ)
#define oVL  (2*S0 + 4*SW + 5*SQ)
#define PREP_TOT (S0 + 2*SW + 3*SQ)   // 2031616 = 7936 * 256

__global__ __launch_bounds__(256) void prep_split_kernel(
    const float* __restrict__ pw_w, const float* __restrict__ Wo, const float* __restrict__ W,
    const float* __restrict__ Wq, const float* __restrict__ Wk, const float* __restrict__ Wv,
    unsigned short* __restrict__ ws) {
  int idx = blockIdx.x * 256 + threadIdx.x;
  const float* src; unsigned short *dh, *dl; int off;
  if (idx < S0)                { src = pw_w; dh = ws + oPwH; dl = ws + oPwL; off = idx; }
  else if (idx < S0 + SW)      { src = Wo;   dh = ws + oWoH; dl = ws + oWoL; off = idx - S0; }
  else if (idx < S0 + 2*SW)    { src = W;    dh = ws + oWH;  dl = ws + oWL;  off = idx - S0 - SW; }
  else if (idx < S0 + 2*SW + SQ)   { src = Wq; dh = ws + oQH; dl = ws + oQL; off = idx - S0 - 2*SW; }
  else if (idx < S0 + 2*SW + 2*SQ) { src = Wk; dh = ws + oKH; dl = ws + oKL; off = idx - S0 - 2*SW - SQ; }
  else                             { src = Wv; dh = ws + oVH; dl = ws + oVL; off = idx - S0 - 2*SW - 2*SQ; }
  float v = src[off];
  unsigned short hi = f2bf(v);
  dh[off] = hi;
  dl[off] = f2bf(v - bf2f(hi));
}

// ---------------- fused [pos-enc +] layernorm [+ depthwise conv] -> bf16 hi/lo ----------------
// vectorized ushort4 stores (obase is 16B-aligned: t*8 ushorts)
typedef unsigned short u16x4 __attribute__((ext_vector_type(4)));
template<bool DO_CONV, bool ADD_PE>
__global__ __launch_bounds__(64) void norm_dw_kernel(const float* __restrict__ in,
                                                     float* __restrict__ cur_out,
                                                     unsigned short* __restrict__ oh,
                                                     unsigned short* __restrict__ ol,
                                                     const float* __restrict__ dww,
                                                     const float* __restrict__ dwb) {
  int row = blockIdx.x;           // b*NC + c
  int c = row & (NC - 1);
  int t = threadIdx.x;
  const float* rp = in + (size_t)row * NL;
  float4 v0 = ((const float4*)rp)[t * 2];
  float4 v1 = ((const float4*)rp)[t * 2 + 1];
  float xr[8] = {v0.x, v0.y, v0.z, v0.w, v1.x, v1.y, v1.z, v1.w};
  if (ADD_PE) {
    int ce = c & ~1;
    double base = exp(-(double)ce * 9.210340371976184 / 128.0); // ln(10000)
    float freq = (c & 1) ? -(float)base : (float)base;
    float phase = (c & 1) ? (float)(M_PI / 2.0) : 0.0f;
#pragma unroll
    for (int j = 0; j < 8; ++j)
      xr[j] += sinf(sinf((float)(t * 8 + j) * freq + phase));
    float4 o0 = make_float4(xr[0], xr[1], xr[2], xr[3]);
    float4 o1 = make_float4(xr[4], xr[5], xr[6], xr[7]);
    float4* cp = (float4*)(cur_out + (size_t)row * NL);
    cp[t * 2] = o0; cp[t * 2 + 1] = o1;
  }
  float s = 0.f;
#pragma unroll
  for (int j = 0; j < 8; ++j) s += xr[j];
#pragma unroll
  for (int off = 32; off >= 1; off >>= 1) s += __shfl_xor(s, off);
  float mean = s * (1.0f / 512.0f);
  float sq = 0.f;
#pragma unroll
  for (int j = 0; j < 8; ++j) { xr[j] -= mean; sq += xr[j] * xr[j]; }
#pragma unroll
  for (int off = 32; off >= 1; off >>= 1) sq += __shfl_xor(sq, off);
  float inv = 1.0f / (sqrtf(sq * (1.0f / 511.0f)) + 1e-6f);

  size_t obase = (size_t)row * NL + t * 8;
  float ov[8];
  if (!DO_CONV) {
#pragma unroll
    for (int j = 0; j < 8; ++j) ov[j] = xr[j] * inv;
  } else {
    __shared__ float rb[NL + 6];
    if (t < 3) { rb[t] = 0.f; rb[NL + 3 + t] = 0.f; }
#pragma unroll
    for (int j = 0; j < 8; ++j) rb[3 + t * 8 + j] = xr[j] * inv;
    __syncthreads();
    float w[7];
#pragma unroll
    for (int u = 0; u < 7; ++u) w[u] = dww[c * 7 + u];
    float bias = dwb[c];
#pragma unroll
    for (int j = 0; j < 8; ++j) {
      int l = t * 8 + j;
      float o = bias;
#pragma unroll
      for (int u = 0; u < 7; ++u) o += rb[l + u] * w[u];
      ov[j] = o;
    }
  }
  u16x4 hv0, hv1, lv0, lv1;
#pragma unroll
  for (int j = 0; j < 4; ++j) {
    unsigned short hi = f2bf(ov[j]);
    hv0[j] = hi; lv0[j] = f2bf(ov[j] - bf2f(hi));
  }
#pragma unroll
  for (int j = 0; j < 4; ++j) {
    unsigned short hi = f2bf(ov[4 + j]);
    hv1[j] = hi; lv1[j] = f2bf(ov[4 + j] - bf2f(hi));
  }
  *(u16x4*)&oh[obase]     = hv0;
  *(u16x4*)&oh[obase + 4] = hv1;
  *(u16x4*)&ol[obase]     = lv0;
  *(u16x4*)&ol[obase + 4] = lv1;
}

// ---------------- MFMA GEMM with pre-split operands ----------------
// A (hi/lo ushort) [M][K]; X (hi/lo ushort) [b][K][L]. 64x64 out per block, 4 waves.
// EPI: 0 = bias+relu+resid+dropout, 1 = resid+dropout, 2 = relu+resid+dropout
template<int EPI, bool A_PER_B>
__global__ __launch_bounds__(256) void gemm_mfma_kernel(
    const unsigned short* __restrict__ AhB, const unsigned short* __restrict__ AlB,
    const unsigned short* __restrict__ XhB, const unsigned short* __restrict__ XlB,
    float* __restrict__ Y, const float* __restrict__ bias, const float* __restrict__ resid,
    uint32_t k0, uint32_t k1) {
  __shared__ unsigned short Ah[64][68], Al[64][68];   // [m][k]
  __shared__ unsigned short Xh[64][68], Xl[64][68];   // [n][k]
  int b  = blockIdx.z;
  int m0 = blockIdx.y * 64;
  int l0 = blockIdx.x * 64;
  int t  = threadIdx.x;
  const int lane = t & 63, w = t >> 6;
  const int g = lane >> 4, j16 = lane & 15;
  const unsigned short* Abh = AhB + (A_PER_B ? (size_t)b * NC * NC : 0);
  const unsigned short* Abl = AlB + (A_PER_B ? (size_t)b * NC * NC : 0);
  const size_t xb = (size_t)b * NC * NL;

  f32x4 acc[4] = {{0.f,0.f,0.f,0.f},{0.f,0.f,0.f,0.f},{0.f,0.f,0.f,0.f},{0.f,0.f,0.f,0.f}};

  for (int kc = 0; kc < 2; ++kc) {
#pragma unroll
    for (int i = 0; i < 4; ++i) {           // A tile: ushort4 copies
      int id = t + i * 256;
      int r = id >> 4, u = (id & 15) << 2;
      *(s16x4*)&Ah[r][u] = *(const s16x4*)&Abh[(size_t)(m0 + r) * NC + kc * 64 + u];
      *(s16x4*)&Al[r][u] = *(const s16x4*)&Abl[(size_t)(m0 + r) * NC + kc * 64 + u];
    }
    {
      int n = t & 63, kq = (t >> 6) * 16;
#pragma unroll
      for (int kk = 0; kk < 16; ++kk) {
        int k = kq + kk;
        size_t src = xb + (size_t)(kc * 64 + k) * NL + l0 + n;
        Xh[n][k] = XhB[src];
        Xl[n][k] = XlB[src];
      }
    }
    __syncthreads();
#pragma unroll
    for (int ks = 0; ks < 4; ++ks) {
      int ko = ks * 16 + 4 * g;
      s16x4 a_h = *(const s16x4*)&Ah[w * 16 + j16][ko];
      s16x4 a_l = *(const s16x4*)&Al[w * 16 + j16][ko];
#pragma unroll
      for (int nt = 0; nt < 4; ++nt) {
        s16x4 x_h = *(const s16x4*)&Xh[nt * 16 + j16][ko];
        s16x4 x_l = *(const s16x4*)&Xl[nt * 16 + j16][ko];
        acc[nt] = mfma_bf16_16x16x16(a_h, x_h, acc[nt]);
        acc[nt] = mfma_bf16_16x16x16(a_l, x_h, acc[nt]);
        acc[nt] = mfma_bf16_16x16x16(a_h, x_l, acc[nt]);
      }
    }
    __syncthreads();
  }

#pragma unroll
  for (int nt = 0; nt < 4; ++nt) {
    int n = l0 + nt * 16 + j16;
#pragma unroll
    for (int r = 0; r < 4; ++r) {
      int m = m0 + w * 16 + 4 * g + r;
      float val = acc[nt][r] + ((EPI == 0) ? bias[m] : 0.0f);
      if (EPI == 0 || EPI == 2) val = fmaxf(val, 0.0f);
      size_t idx = ((size_t)b * NC + m) * NL + n;
      float v2 = resid[idx] + val;
      float ds = drop_scale(k0, k1, (uint32_t)idx);
      Y[idx] = (ds == 0.0f) ? 0.0f : (v2 / 0.9f);
    }
  }
}

// ---------------- MFMA QKV projection with pre-split operands ----------------
__global__ __launch_bounds__(256) void qkv_mfma_kernel(
    const unsigned short* __restrict__ wsp,
    const unsigned short* __restrict__ XhB, const unsigned short* __restrict__ XlB,
    unsigned short* __restrict__ qhw, unsigned short* __restrict__ qlw,
    unsigned short* __restrict__ khw, unsigned short* __restrict__ klw,
    unsigned short* __restrict__ vbw) {
  __shared__ unsigned short Ah[64][68], Al[64][68];
  __shared__ unsigned short Xh[64][68], Xl[64][68];
  int b  = blockIdx.z;
  int m0 = blockIdx.y * 64;          // sel = m0>>7 uniform per block
  int l0 = blockIdx.x * 64;
  int t  = threadIdx.x;
  const int lane = t & 63, w = t >> 6;
  const int g = lane >> 4, j16 = lane & 15;
  const int sel = m0 >> 7;
  const unsigned short* WpH = wsp + ((sel == 0) ? oQH : (sel == 1) ? oKH : oVH);
  const unsigned short* WpL = wsp + ((sel == 0) ? oQL : (sel == 1) ? oKL : oVL);
  const size_t xb = (size_t)b * NC * NL;

  f32x4 acc[4] = {{0.f,0.f,0.f,0.f},{0.f,0.f,0.f,0.f},{0.f,0.f,0.f,0.f},{0.f,0.f,0.f,0.f}};

  for (int kc = 0; kc < 2; ++kc) {
#pragma unroll
    for (int i = 0; i < 4; ++i) {
      int id = t + i * 256;
      int r = id >> 4, u = (id & 15) << 2;
      int gr = m0 + r;
      int w_ = gr & 127, h = w_ >> 4, kk = w_ & 15;
      size_t rowoff = (((size_t)h * NB + b) * NDK + kk) * NC + kc * 64 + u;
      *(s16x4*)&Ah[r][u] = *(const s16x4*)&WpH[rowoff];
      *(s16x4*)&Al[r][u] = *(const s16x4*)&WpL[rowoff];
    }
    {
      int n = t & 63, kq = (t >> 6) * 16;
#pragma unroll
      for (int kk = 0; kk < 16; ++kk) {
        int k = kq + kk;
        size_t src = xb + (size_t)(kc * 64 + k) * NL + l0 + n;
        Xh[n][k] = XhB[src];
        Xl[n][k] = XlB[src];
      }
    }
    __syncthreads();
#pragma unroll
    for (int ks = 0; ks < 4; ++ks) {
      int ko = ks * 16 + 4 * g;
      s16x4 a_h = *(const s16x4*)&Ah[w * 16 + j16][ko];
      s16x4 a_l = *(const s16x4*)&Al[w * 16 + j16][ko];
#pragma unroll
      for (int nt = 0; nt < 4; ++nt) {
        s16x4 x_h = *(const s16x4*)&Xh[nt * 16 + j16][ko];
        s16x4 x_l = *(const s16x4*)&Xl[nt * 16 + j16][ko];
        acc[nt] = mfma_bf16_16x16x16(a_h, x_h, acc[nt]);
        acc[nt] = mfma_bf16_16x16x16(a_l, x_h, acc[nt]);
        acc[nt] = mfma_bf16_16x16x16(a_h, x_l, acc[nt]);
      }
    }
    __syncthreads();
  }

#pragma unroll
  for (int nt = 0; nt < 4; ++nt) {
    int n = l0 + nt * 16 + j16;
#pragma unroll
    for (int r = 0; r < 4; ++r) {
      int grow = m0 + w * 16 + 4 * g + r;
      int w_ = grow & 127, h = w_ >> 4, kk = w_ & 15;
      size_t idx = (((size_t)h * NB + b) * NDK + kk) * NL + n;
      float v = acc[nt][r];
      if (sel == 0) {
        float sv = v * 0.25f;
        unsigned short hi = f2bf(sv);
        qhw[idx] = hi; qlw[idx] = f2bf(sv - bf2f(hi));
      } else if (sel == 1) {
        unsigned short hi = f2bf(v);
        khw[idx] = hi; klw[idx] = f2bf(v - bf2f(hi));
      } else {
        vbw[idx] = f2bf(v);
      }
    }
  }
}

// ---------------- MFMA attention, fully LDS-resident (softmax over query axis i) ----------------
// grid: dim3(4, H*B); 256 thr = 4 waves; wave owns 2 j-tiles of 16. Zero barriers in loop.
// Output: head hi/lo bf16 (feeds Wo GEMM directly).
__global__ __launch_bounds__(256) void attn_kernel(const unsigned short* __restrict__ qh,
                                                   const unsigned short* __restrict__ ql,
                                                   const unsigned short* __restrict__ kh,
                                                   const unsigned short* __restrict__ kl,
                                                   const unsigned short* __restrict__ vb,
                                                   unsigned short* __restrict__ oh,
                                                   unsigned short* __restrict__ ol) {
  __shared__ unsigned short QtH[512][16], QtL[512][16];   // 16 KB each, [i][k]
  __shared__ unsigned short KtH[128][16], KtL[128][16];   // 4 KB each,  [j][k]
  __shared__ unsigned short Vt[16][520];                  // 16.25 KB,   [v][i] (+pad)
  const int t = threadIdx.x;
  const int lane = t & 63, w = t >> 6;
  const int g = lane >> 4, j16 = lane & 15;
  const int hb = blockIdx.y, jq = blockIdx.x;
  const int j0 = jq * 128;
  const int h = hb / NB, b = hb % NB;
  const size_t kb = (size_t)hb * NDK * NL;

  // stage Q hi/lo transposed [i][k] (coalesced over i)
  for (int n = 0; n < 32; ++n) {
    int e = n * 256 + t;
    int k = e >> 9, i = e & 511;
    QtH[i][k] = qh[kb + (size_t)k * NL + i];
    QtL[i][k] = ql[kb + (size_t)k * NL + i];
  }
  // stage V [v][i] (uint32 = 2 ushorts)
  for (int n = 0; n < 16; ++n) {
    int e = n * 256 + t;            // 4096 u32 units
    int v = e >> 8, i2 = e & 255;
    *(uint32_t*)&Vt[v][i2 * 2] = *(const uint32_t*)&vb[kb + (size_t)v * NL + i2 * 2];
  }
  // stage K quarter [j][k]
  for (int n = 0; n < 8; ++n) {
    int e = n * 256 + t;
    int k = e >> 7, j = e & 127;
    KtH[j][k] = kh[kb + (size_t)k * NL + j0 + j];
    KtL[j][k] = kl[kb + (size_t)k * NL + j0 + j];
  }
  __syncthreads();

  s16x4 KhiF[2], KloF[2];
#pragma unroll
  for (int q = 0; q < 2; ++q) {
    int jj = (w * 2 + q) * 16 + j16;
    KhiF[q] = *(const s16x4*)&KtH[jj][4 * g];
    KloF[q] = *(const s16x4*)&KtL[jj][4 * g];
  }

  float Mq[2] = {-INFINITY, -INFINITY};
  float lq[2] = {0.f, 0.f};
  f32x4 hC[2] = {{0.f, 0.f, 0.f, 0.f}, {0.f, 0.f, 0.f, 0.f}};

  for (int it = 0; it < 32; ++it) {
    s16x4 Qhi = *(const s16x4*)&QtH[it * 16 + j16][4 * g];
    s16x4 Qlo = *(const s16x4*)&QtL[it * 16 + j16][4 * g];
    s16x4 Vf  = *(const s16x4*)&Vt[j16][it * 16 + 4 * g];
#pragma unroll
    for (int q = 0; q < 2; ++q) {
      f32x4 S = {0.f, 0.f, 0.f, 0.f};
      S = mfma_bf16_16x16x16(Qhi, KhiF[q], S);
      S = mfma_bf16_16x16x16(Qlo, KhiF[q], S);
      S = mfma_bf16_16x16x16(Qhi, KloF[q], S);
      float tm = fmaxf(fmaxf(S[0], S[1]), fmaxf(S[2], S[3]));
      tm = fmaxf(tm, __shfl_xor(tm, 16));
      tm = fmaxf(tm, __shfl_xor(tm, 32));
      float Mn = fmaxf(Mq[q], tm);
      float corr = __expf(Mq[q] - Mn);
      Mq[q] = Mn;
      float p0 = __expf(S[0] - Mn), p1 = __expf(S[1] - Mn);
      float p2 = __expf(S[2] - Mn), p3 = __expf(S[3] - Mn);
      lq[q] = lq[q] * corr + ((p0 + p1) + (p2 + p3));
      hC[q] = hC[q] * corr;
      union { uint32_t u[2]; s16x4 s; } bp;
      bp.u[0] = (uint32_t)f2bf(p0) | ((uint32_t)f2bf(p1) << 16);
      bp.u[1] = (uint32_t)f2bf(p2) | ((uint32_t)f2bf(p3) << 16);
      hC[q] = mfma_bf16_16x16x16(Vf, bp.s, hC[q]);
    }
  }

#pragma unroll
  for (int q = 0; q < 2; ++q) {
    float l2 = lq[q] + __shfl_xor(lq[q], 16);
    float L  = l2 + __shfl_xor(l2, 32);
    float invL = 1.0f / L;
    int jglob = j0 + (w * 2 + q) * 16 + j16;
#pragma unroll
    for (int r = 0; r < 4; ++r) {
      float val = hC[q][r] * invL;
      size_t idx = ((size_t)b * NC + h * NDK + 4 * g + r) * NL + jglob;
      unsigned short hi = f2bf(val);
      oh[idx] = hi;
      ol[idx] = f2bf(val - bf2f(hi));
    }
  }
}

// ---------------- launch ----------------
extern "C" void kernel_launch(void* const* d_in, const int* in_sizes, int n_in,
                              void* d_out, int out_size, void* d_ws, size_t ws_size,
                              hipStream_t stream) {
  (void)in_sizes; (void)n_in; (void)out_size; (void)ws_size;
  const float* x    = (const float*)d_in[0];
  const float* dw_w = (const float*)d_in[1];
  const float* dw_b = (const float*)d_in[2];
  const float* pw_w = (const float*)d_in[3];
  const float* pw_b = (const float*)d_in[4];
  const float* Wq   = (const float*)d_in[5];
  const float* Wk   = (const float*)d_in[6];
  const float* Wv   = (const float*)d_in[7];
  const float* Wo   = (const float*)d_in[8];
  const float* W    = (const float*)d_in[9];
  float* out = (float*)d_out;

  const size_t N = NTOT;
  float* cur = (float*)d_ws;                      // N floats
  unsigned short* XhB = (unsigned short*)(cur + N);
  unsigned short* XlB = XhB + N;
  unsigned short* qh  = XlB + N;
  unsigned short* ql  = qh + N;
  unsigned short* kh  = ql + N;
  unsigned short* kl  = kh + N;
  unsigned short* vb  = kl + N;
  unsigned short* wsp = vb + N;                   // weight-split arena (PREP ushorts)

  uint32_t fk0[6], fk1[6];
  for (int i = 0; i < 6; ++i) {
    uint32_t a = 0u, bb = (uint32_t)i;
    tf2x32(0u, 7u, a, bb);
    fk0[i] = a; fk1[i] = bb;
  }

  prep_split_kernel<<<PREP_TOT / 256, 256, 0, stream>>>(pw_w, Wo, W, Wq, Wk, Wv, wsp);

  // conv block 0: pos-enc fused
  norm_dw_kernel<true, true><<<NB * NC, 64, 0, stream>>>(x, cur, XhB, XlB, dw_w, dw_b);
  gemm_mfma_kernel<0, false><<<dim3(8, 2, NB), 256, 0, stream>>>(
      wsp + oPwH, wsp + oPwL, XhB, XlB, cur, pw_b, cur, fk0[0], fk1[0]);
  for (int ci = 1; ci < 4; ++ci) {
    norm_dw_kernel<true, false><<<NB * NC, 64, 0, stream>>>(cur, nullptr, XhB, XlB,
                                                            dw_w + ci * NC * 7, dw_b + ci * NC);
    gemm_mfma_kernel<0, false><<<dim3(8, 2, NB), 256, 0, stream>>>(
        wsp + oPwH + (size_t)ci * NC * NC, wsp + oPwL + (size_t)ci * NC * NC,
        XhB, XlB, cur, pw_b + ci * NC, cur, fk0[ci], fk1[ci]);
  }

  norm_dw_kernel<false, false><<<NB * NC, 64, 0, stream>>>(cur, nullptr, XhB, XlB, nullptr, nullptr);
  qkv_mfma_kernel<<<dim3(8, 6, NB), 256, 0, stream>>>(wsp, XhB, XlB, qh, ql, kh, kl, vb);
  attn_kernel<<<dim3(4, NH * NB), 256, 0, stream>>>(qh, ql, kh, kl, vb, XhB, XlB);
  gemm_mfma_kernel<1, true><<<dim3(8, 2, NB), 256, 0, stream>>>(
      wsp + oWoH, wsp + oWoL, XhB, XlB, cur, nullptr, cur, fk0[4], fk1[4]);

  norm_dw_kernel<false, false><<<NB * NC, 64, 0, stream>>>(cur, nullptr, XhB, XlB, nullptr, nullptr);
  gemm_mfma_kernel<2, true><<<dim3(8, 2, NB), 256, 0, stream>>>(
      wsp + oWH, wsp + oWL, XhB, XlB, out, nullptr, cur, fk0[5], fk1[5]);
}